// Round 8
// baseline (151.776 us; speedup 1.0000x reference)
//
#include <hip/hip_runtime.h>
#include <hip/hip_fp16.h>
#include <math.h>

// CTC forward loss (warp-ctc semantics). T=1024, B=64, V=128, L=256, S=513.
//
// Round 9: DP staging via global_load_lds (direct-to-LDS DMA, no VGPR
// buffers). R7 proved the register allocator will not hold a 48-load asm
// pipeline (VGPR=84 vs needed 128+ -> partial spill, slower). Here:
// double-buffered LDS (2 x 8448 B), 9 DMA loads per 16-step block
// (8 x width-16 for P rows + 1 x width-4 for blanks), counted
// s_waitcnt vmcnt(9) per block (never 0), lgkmcnt(0) drain before
// re-staging a buffer (DMA-vs-ds_read race), sched_barrier(0) after each
// wait (rule #18). Per-step consumption: 2 x ds_read_b64 from LDS.
// Packed-FP32 VOP3P step + off-critical-path renorm unchanged from R6.

#define L2E 1.4426950408889634f
#define LN2 0.6931471805599453f

constexpr int T   = 1024;
constexpr int B   = 64;
constexpr int V   = 128;
constexpr int L   = 256;
constexpr int RW  = 256;        // ushorts per P row: 256 label probs = 512 B
constexpr int TP  = T + 32;     // padded time rows per batch

// LDS layout (uints): per buffer 2112 uints = 2048 (16 rows x 512 B) + 64
// (256 B blank stage, first 32 uints = 16 fp32 pairs used).
constexpr int LBUF = 2112;

typedef float v2f __attribute__((ext_vector_type(2)));
typedef unsigned int v2u __attribute__((ext_vector_type(2)));

// ---- VOP3P packed-fp32 helpers (gfx90a+; full-rate dual fp32) ----
__device__ __forceinline__ v2f pk_add(v2f a, v2f b) {
  v2f d; asm("v_pk_add_f32 %0, %1, %2" : "=v"(d) : "v"(a), "v"(b)); return d;
}
__device__ __forceinline__ v2f pk_mul(v2f a, v2f b) {
  v2f d; asm("v_pk_mul_f32 %0, %1, %2" : "=v"(d) : "v"(a), "v"(b)); return d;
}
__device__ __forceinline__ v2f pk_fma(v2f a, v2f b, v2f c) {
  v2f d; asm("v_pk_fma_f32 %0, %1, %2, %3" : "=v"(d) : "v"(a), "v"(b), "v"(c));
  return d;
}

// ---- direct-to-LDS DMA ----
typedef __attribute__((address_space(3))) unsigned int as3_uint;
typedef __attribute__((address_space(1))) unsigned int as1_uint;
__device__ __forceinline__ void gl_lds16(const uint* g, uint* l) {
  __builtin_amdgcn_global_load_lds((const as1_uint*)g, (as3_uint*)l, 16, 0, 0);
}
__device__ __forceinline__ void gl_lds4(const uint* g, uint* l) {
  __builtin_amdgcn_global_load_lds((const as1_uint*)g, (as3_uint*)l, 4, 0, 0);
}

// ---- DPP helpers (gfx9 ctrl codes: 0x111+ row_shr, 0x138 wave_shr:1,
//      0x142 row_bcast15, 0x143 row_bcast31) ----
template <int CTRL>
__device__ __forceinline__ float fdpp0(float x) {        // invalid lanes -> 0
  return __int_as_float(__builtin_amdgcn_update_dpp(
      0, __float_as_int(x), CTRL, 0xf, 0xf, true));
}
template <int CTRL>
__device__ __forceinline__ float fdppk(float x) {        // invalid lanes -> keep
  return __int_as_float(__builtin_amdgcn_update_dpp(
      __float_as_int(x), __float_as_int(x), CTRL, 0xf, 0xf, false));
}

__device__ __forceinline__ float wave_bcast63(float x) {
  return __int_as_float(__builtin_amdgcn_readlane(__float_as_int(x), 63));
}

__device__ __forceinline__ float wave_max(float x) {     // any sign
  x = fmaxf(x, fdppk<0x111>(x));
  x = fmaxf(x, fdppk<0x112>(x));
  x = fmaxf(x, fdppk<0x114>(x));
  x = fmaxf(x, fdppk<0x118>(x));
  x = fmaxf(x, fdppk<0x142>(x));
  x = fmaxf(x, fdppk<0x143>(x));
  return wave_bcast63(x);
}
__device__ __forceinline__ float wave_sum_nn(float x) {  // x >= 0
  x += fdpp0<0x111>(x);
  x += fdpp0<0x112>(x);
  x += fdpp0<0x114>(x);
  x += fdpp0<0x118>(x);
  x += fdpp0<0x142>(x);
  x += fdpp0<0x143>(x);
  return wave_bcast63(x);
}

__device__ __forceinline__ float h2f(uint bits) {
  return __half2float(__ushort_as_half((ushort)bits));
}

// ---------------- prologue: emission probabilities ----------------
// One wave per (t, b) row. Softmax entirely in registers; ds_bpermute label
// gathers. Output PAIRED for the DP: u.x=(e0|e2<<16), u.y=(e1|e3<<16).
// Blank(t) stored as a duplicated fp32 pair at pair index t+1 (so 16-step
// blocks start 16B-aligned for the DP's staging).
__global__ __launch_bounds__(512) void ctc_probs_kernel(
    const float* __restrict__ acts,        // (T, B, V)
    const int* __restrict__ labels,        // (B, L)
    ushort* __restrict__ P,                // (B, TP, RW) fp16 bits, 512B rows
    float* __restrict__ Pbk) {             // (B, TP pairs)
  const int w    = threadIdx.x >> 6;
  const int lane = threadIdx.x & 63;
  const int t    = blockIdx.x * 8 + w;     // t in [0, TP)
  const int b    = blockIdx.y;
  ushort* prow = P + ((size_t)b * TP + t) * RW;

  if (t >= T) {                            // zero pad P row (content unused)
    uint2 z; z.x = 0u; z.y = 0u;
    *(uint2*)(prow + 4 * lane) = z;
    return;
  }

  const float* row = acts + ((size_t)t * B + b) * V;
  const float2 v2 = *(const float2*)(row + 2 * lane);
  const float e0 = exp2f(fmaf(v2.x, L2E, -32.0f));
  const float e1 = exp2f(fmaf(v2.y, L2E, -32.0f));
  const float sm = wave_sum_nn(e0 + e1);
  const float r  = __builtin_amdgcn_rcpf(sm);

  const auto pk = __builtin_amdgcn_cvt_pkrtz(e0 * r, e1 * r);
  uint hp;                                  // [p_{2l} | p_{2l+1} << 16]
  __builtin_memcpy(&hp, &pk, 4);

  // gather the 4 label probs this lane owns (labels 4l..4l+3)
  const int4 lv = *(const int4*)(labels + (size_t)b * L + 4 * lane);
  const uint g0 = (uint)__builtin_amdgcn_ds_bpermute((lv.x & ~1) * 2, (int)hp);
  const uint g1 = (uint)__builtin_amdgcn_ds_bpermute((lv.y & ~1) * 2, (int)hp);
  const uint g2 = (uint)__builtin_amdgcn_ds_bpermute((lv.z & ~1) * 2, (int)hp);
  const uint g3 = (uint)__builtin_amdgcn_ds_bpermute((lv.w & ~1) * 2, (int)hp);
  const uint h0 = (g0 >> ((lv.x & 1) << 4)) & 0xffffu;
  const uint h1 = (g1 >> ((lv.y & 1) << 4)) & 0xffffu;
  const uint h2 = (g2 >> ((lv.z & 1) << 4));
  const uint h3 = (g3 >> ((lv.w & 1) << 4));
  uint2 o;
  o.x = h0 | (h2 << 16);                    // pair (e0, e2)
  o.y = h1 | (h3 << 16);                    // pair (e1, e3)
  *(uint2*)(prow + 4 * lane) = o;
  if (lane == 0) {
    const float pb = e0 * r;                // vocab 0 = this lane's p0
    v2f bp; bp.x = pb; bp.y = pb;
    *(v2f*)(Pbk + ((size_t)b * TP + t + 1) * 2) = bp;
  }
}

// ---------------- DP kernel: one wave per batch ----------------
// Lane l owns cells 8l..8l+7 as pairs P0=(c0,c4) P1=(c1,c5) P2=(c2,c6)
// P3=(c3,c7); lane 63 additionally owns cell 512 in a8.
__global__ __launch_bounds__(64, 1) void ctc_dp_kernel(
    const ushort* __restrict__ P,
    const float* __restrict__ Pbk,
    const int* __restrict__ labels,
    const int* __restrict__ act_lens,
    const int* __restrict__ label_lens,
    float* __restrict__ out) {
  __shared__ uint lds[2 * LBUF];
  const int b    = blockIdx.x;
  const int lane = threadIdx.x;
  const ushort* __restrict__ Pb = P + (size_t)b * TP * RW;
  const float*  __restrict__ Bk = Pbk + (size_t)b * TP * 2;

  // skip-transition flags for the 4 odd cells (labels 4l..4l+3)
  const int4 lv   = *(const int4*)(labels + (size_t)b * L + 4 * lane);
  const int prevw = __builtin_amdgcn_update_dpp(0, lv.w, 0x138, 0xf, 0xf, true);
  const float f0 = (lane > 0 && lv.x != 0 && lv.x != prevw) ? 1.f : 0.f;
  const float f1 = (lv.y != 0 && lv.y != lv.x) ? 1.f : 0.f;
  const float f2 = (lv.z != 0 && lv.z != lv.y) ? 1.f : 0.f;
  const float f3 = (lv.w != 0 && lv.w != lv.z) ? 1.f : 0.f;
  v2f F02; F02.x = f0; F02.y = f2;          // skips into P1 = (c1, c5)
  v2f F13; F13.x = f1; F13.y = f3;          // skips into P3 = (c3, c7)

  const int AL = act_lens[b];

  // ---- t=0 init (linear domain; unreachable cells = 0) ----
  v2f P0, P1, P2, P3;
  P0.x=0.f; P0.y=0.f; P1.x=0.f; P1.y=0.f;
  P2.x=0.f; P2.y=0.f; P3.x=0.f; P3.y=0.f;
  float a8 = 0.f;
  {
    const uint2 u0 = *(const uint2*)(Pb + 4 * lane);
    const float eb0 = Bk[2];                // blank(t=0) at pair 1
    const float e00 = h2f(u0.x);            // label-0 prob at t=0 (pair lo)
    if (lane == 0) { P0.x = eb0; P1.x = e00; }
  }
  int iacc = 0;        // accumulated log2 of renorm scales (wave-uniform)
  float pend = 1.0f;   // wave-maxed state max, measured 4 steps before apply

  // Packed step: 1 DPP + 4 pk_add + 2 pk_fma + 4 pk_mul (+ a8 scalar pair).
  auto step = [&](v2u u, v2f eb) {
    const float pc = fdpp0<0x138>(P3.y);    // prev lane's c7 (lane0 -> 0)
    v2f Q; Q.x = pc; Q.y = P3.x;            // (c_{-1}, c3_old)
    v2f E02, E13;
    E02.x = h2f(u.x); E02.y = h2f(u.x >> 16);
    E13.x = h2f(u.y); E13.y = h2f(u.y >> 16);
    const v2f S0 = pk_add(P0, Q);           // (c0+pc,  c4+c3)
    const v2f S1 = pk_add(P1, P0);          // (c1+c0,  c5+c4)
    const v2f S2 = pk_add(P2, P1);          // (c2+c1,  c6+c5)
    const v2f S3 = pk_add(P3, P2);          // (c3+c2,  c7+c6)
    const v2f T1 = pk_fma(F02, Q,  S1);     // +f0*pc,  +f2*c3_old
    const v2f T3 = pk_fma(F13, P1, S3);     // +f1*c1_old, +f3*c5_old
    const float s8 = a8 + P3.y;             // cell 512 (valid on lane 63)
    P0 = pk_mul(S0, eb);
    P2 = pk_mul(S2, eb);
    P1 = pk_mul(T1, E02);
    P3 = pk_mul(T3, E13);
    a8 = s8 * eb.x;
  };

  auto measure = [&]() {                    // start wave-max; result used 4
    float m = fmaxf(fmaxf(fmaxf(P0.x, P0.y), fmaxf(P1.x, P1.y)),   // steps later
                    fmaxf(fmaxf(P2.x, P2.y), fmaxf(P3.x, P3.y)));
    m = fmaxf(m, a8);
    pend = wave_max(m);
  };
  auto apply = [&]() {                      // pow-2 scale, exact
    const uint mb = __float_as_uint(pend);
    int e = (int)((mb >> 23) & 0xffu); if (e < 1) e = 1;
    const float r = __uint_as_float((uint)(254 - e) << 23);
    iacc += (e - 127);
    v2f rr; rr.x = r; rr.y = r;
    P0 = pk_mul(P0, rr); P1 = pk_mul(P1, rr);
    P2 = pk_mul(P2, rr); P3 = pk_mul(P3, rr);
    a8 *= r;
  };

  // ---- staging: 9 DMA loads per 16-step block into LDS buffer bufi ----
  // P rows: 8 x width-16 (64 lanes x 16 B = 1024 B = 2 rows each).
  // Blanks: 1 x width-4 (256 B; first 128 B used). Max byte read:
  // P: (1+16*63)*512 + 8191 + lane*16 < TP*512; Bk: 8080+256 <= TP*8. OK.
  auto stage = [&](int bufi, int pblk) {
    uint* lb = &lds[bufi * LBUF];
    const uint* gp = (const uint*)(Pb + (size_t)(1 + 16 * pblk) * RW) + lane * 4;
    #pragma unroll
    for (int r2 = 0; r2 < 8; ++r2)
      gl_lds16(gp + r2 * 256, lb + r2 * 256);
    const uint* gb = (const uint*)(Bk + (size_t)(2 + 16 * pblk) * 2) + lane;
    gl_lds4(gb, lb + 2048);
  };

  auto compute_blk = [&](int bufi, int tb, bool fast) {
    const uint* lb = &lds[bufi * LBUF];
    if (fast) {
      #pragma unroll
      for (int k = 0; k < 16; ++k) {
        const v2u u = *(const v2u*)(lb + k * 128 + lane * 2);
        const v2f eb = *(const v2f*)(lb + 2048 + 2 * k);
        step(u, eb);
        if (k == 3 || k == 11) measure();
        if (k == 7 || k == 15) apply();
      }
    } else {
      #pragma unroll
      for (int k = 0; k < 16; ++k) {
        const v2u u = *(const v2u*)(lb + k * 128 + lane * 2);
        const v2f eb = *(const v2f*)(lb + 2048 + 2 * k);
        if ((tb + k) < AL) step(u, eb);     // AL wave-uniform: scalar branch
        if (k == 3 || k == 11) measure();
        if (k == 7 || k == 15) apply();
      }
    }
  };

  stage(0, 0);
  stage(1, 1);

  int t0 = 1;
  #pragma unroll 1
  for (int it = 0; it < 64; ++it) {
    const int cur = it & 1;
    asm volatile("s_waitcnt vmcnt(9)" ::: "memory");    // block `it` landed
    __builtin_amdgcn_sched_barrier(0);
    compute_blk(cur, t0, (t0 + 16) <= AL);
    asm volatile("s_waitcnt lgkmcnt(0)" ::: "memory");  // buf reads done
    __builtin_amdgcn_sched_barrier(0);
    int nb = it + 2; if (nb > 63) nb = 63;              // clamped: vmcnt const
    stage(cur, nb);
    t0 += 16;
  }

  // ---- epilogue: -ln( (a[end] + a[end-1]) * 2^iacc ) ----
  // cell map: base+0=P0.x +1=P1.x +2=P2.x +3=P3.x +4=P0.y +5=P1.y +6=P2.y +7=P3.y
  const int end  = 2 * label_lens[b];
  const int base = 8 * lane;
  float sel = 0.f;
  if (base     == end || base     == end - 1) sel += P0.x;
  if (base + 1 == end || base + 1 == end - 1) sel += P1.x;
  if (base + 2 == end || base + 2 == end - 1) sel += P2.x;
  if (base + 3 == end || base + 3 == end - 1) sel += P3.x;
  if (base + 4 == end || base + 4 == end - 1) sel += P0.y;
  if (base + 5 == end || base + 5 == end - 1) sel += P1.y;
  if (base + 6 == end || base + 6 == end - 1) sel += P2.y;
  if (base + 7 == end || base + 7 == end - 1) sel += P3.y;
  if (lane == 63 && (end == 512 || end - 1 == 512)) sel += a8;
  sel = wave_sum_nn(sel);
  if (lane == 0) {
    const float cost = -((log2f(sel) + (float)iacc) * LN2);
    atomicAdd(out, cost);
  }
}

extern "C" void kernel_launch(void* const* d_in, const int* in_sizes, int n_in,
                              void* d_out, int out_size, void* d_ws, size_t ws_size,
                              hipStream_t stream) {
  const float* acts       = (const float*)d_in[0];
  const int*   labels     = (const int*)d_in[1];
  const int*   act_lens   = (const int*)d_in[2];
  const int*   label_lens = (const int*)d_in[3];
  float* out = (float*)d_out;
  ushort* P   = (ushort*)d_ws;                       // B*TP*512B = 34.6 MB
  float*  Pbk = (float*)(P + (size_t)B * TP * RW);   // B*TP*8B   = 0.54 MB

  (void)hipMemsetAsync(out, 0, sizeof(float) * out_size, stream);
  ctc_probs_kernel<<<dim3(TP / 8, B), 512, 0, stream>>>(acts, labels, P, Pbk);
  ctc_dp_kernel<<<B, 64, 0, stream>>>(P, Pbk, labels, act_lens, label_lens, out);
}

// Round 9
// 150.489 us; speedup vs baseline: 1.0086x; 1.0086x over previous
//
#include <hip/hip_runtime.h>
#include <hip/hip_fp16.h>
#include <math.h>

// CTC forward loss (warp-ctc semantics). T=1024, B=64, V=128, L=256, S=513.
//
// Round 10: explicit 4-deep ds_read software pipeline. R2/R4/R7/R8 show a
// ~60-75 cyc/step stall invariant across staging schemes; in R8 the only
// per-step memory ops are 2x ds_read_b64 (u, eb) and the compiler hoists
// them only ~1-2 steps ahead across the serial DP recurrence -> exposed
// ~120cyc LDS latency. Fix: rotating 4-pair register pipeline (16 VGPRs),
// all ds_reads + waits in volatile asm; each step's s_waitcnt lgkmcnt(8)
// is dataflow-tied to the consumed (u,eb) so neither the wait nor the
// consumer can be rescheduled (rule #18 via dataflow). Block tail drains
// lgkmcnt to 0 (also makes DMA re-staging race-free); block head keeps
// counted vmcnt(9). Staging/step math unchanged from R8.

#define L2E 1.4426950408889634f
#define LN2 0.6931471805599453f

constexpr int T   = 1024;
constexpr int B   = 64;
constexpr int V   = 128;
constexpr int L   = 256;
constexpr int RW  = 256;        // ushorts per P row: 256 label probs = 512 B
constexpr int TP  = T + 32;     // padded time rows per batch

// LDS layout (uints): per buffer 2112 uints = 2048 (16 rows x 512 B) + 64
// (256 B blank stage, first 32 uints = 16 fp32 pairs used).
constexpr int LBUF = 2112;      // uints; 8448 bytes

typedef float v2f __attribute__((ext_vector_type(2)));
typedef unsigned int v2u __attribute__((ext_vector_type(2)));

// ---- VOP3P packed-fp32 helpers (gfx90a+; full-rate dual fp32) ----
__device__ __forceinline__ v2f pk_add(v2f a, v2f b) {
  v2f d; asm("v_pk_add_f32 %0, %1, %2" : "=v"(d) : "v"(a), "v"(b)); return d;
}
__device__ __forceinline__ v2f pk_mul(v2f a, v2f b) {
  v2f d; asm("v_pk_mul_f32 %0, %1, %2" : "=v"(d) : "v"(a), "v"(b)); return d;
}
__device__ __forceinline__ v2f pk_fma(v2f a, v2f b, v2f c) {
  v2f d; asm("v_pk_fma_f32 %0, %1, %2, %3" : "=v"(d) : "v"(a), "v"(b), "v"(c));
  return d;
}

// ---- direct-to-LDS DMA ----
typedef __attribute__((address_space(3))) unsigned int as3_uint;
typedef __attribute__((address_space(1))) unsigned int as1_uint;
__device__ __forceinline__ void gl_lds16(const uint* g, uint* l) {
  __builtin_amdgcn_global_load_lds((const as1_uint*)g, (as3_uint*)l, 16, 0, 0);
}
__device__ __forceinline__ void gl_lds4(const uint* g, uint* l) {
  __builtin_amdgcn_global_load_lds((const as1_uint*)g, (as3_uint*)l, 4, 0, 0);
}

// ---- asm ds_read into pinned registers (addr = raw LDS byte offset) ----
template <int OFF>
__device__ __forceinline__ void dsr64(v2u& d, uint a) {
  asm volatile("ds_read_b64 %0, %1 offset:%2"
               : "=v"(d) : "v"(a), "i"(OFF) : "memory");
}
template <int OFF>
__device__ __forceinline__ void dsr64f(v2f& d, uint a) {
  asm volatile("ds_read_b64 %0, %1 offset:%2"
               : "=v"(d) : "v"(a), "i"(OFF) : "memory");
}
// dataflow-ordered wait: reads-writes the consumed pair so the wait sits
// after their defining ds_read and before their consumers.
template <int N>
__device__ __forceinline__ void waitpair(v2u& u, v2f& e) {
  asm volatile("s_waitcnt lgkmcnt(%2)" : "+v"(u), "+v"(e) : "i"(N));
}

// ---- DPP helpers (gfx9 ctrl codes: 0x111+ row_shr, 0x138 wave_shr:1,
//      0x142 row_bcast15, 0x143 row_bcast31) ----
template <int CTRL>
__device__ __forceinline__ float fdpp0(float x) {        // invalid lanes -> 0
  return __int_as_float(__builtin_amdgcn_update_dpp(
      0, __float_as_int(x), CTRL, 0xf, 0xf, true));
}
template <int CTRL>
__device__ __forceinline__ float fdppk(float x) {        // invalid lanes -> keep
  return __int_as_float(__builtin_amdgcn_update_dpp(
      __float_as_int(x), __float_as_int(x), CTRL, 0xf, 0xf, false));
}

__device__ __forceinline__ float wave_bcast63(float x) {
  return __int_as_float(__builtin_amdgcn_readlane(__float_as_int(x), 63));
}

__device__ __forceinline__ float wave_max(float x) {     // any sign
  x = fmaxf(x, fdppk<0x111>(x));
  x = fmaxf(x, fdppk<0x112>(x));
  x = fmaxf(x, fdppk<0x114>(x));
  x = fmaxf(x, fdppk<0x118>(x));
  x = fmaxf(x, fdppk<0x142>(x));
  x = fmaxf(x, fdppk<0x143>(x));
  return wave_bcast63(x);
}
__device__ __forceinline__ float wave_sum_nn(float x) {  // x >= 0
  x += fdpp0<0x111>(x);
  x += fdpp0<0x112>(x);
  x += fdpp0<0x114>(x);
  x += fdpp0<0x118>(x);
  x += fdpp0<0x142>(x);
  x += fdpp0<0x143>(x);
  return wave_bcast63(x);
}

__device__ __forceinline__ float h2f(uint bits) {
  return __half2float(__ushort_as_half((ushort)bits));
}

// ---------------- prologue: emission probabilities ----------------
// One wave per (t, b) row. Softmax entirely in registers; ds_bpermute label
// gathers. Output PAIRED for the DP: u.x=(e0|e2<<16), u.y=(e1|e3<<16).
// Blank(t) stored as a duplicated fp32 pair at pair index t+1 (so 16-step
// blocks start 16B-aligned for the DP's staging).
__global__ __launch_bounds__(512) void ctc_probs_kernel(
    const float* __restrict__ acts,        // (T, B, V)
    const int* __restrict__ labels,        // (B, L)
    ushort* __restrict__ P,                // (B, TP, RW) fp16 bits, 512B rows
    float* __restrict__ Pbk) {             // (B, TP pairs)
  const int w    = threadIdx.x >> 6;
  const int lane = threadIdx.x & 63;
  const int t    = blockIdx.x * 8 + w;     // t in [0, TP)
  const int b    = blockIdx.y;
  ushort* prow = P + ((size_t)b * TP + t) * RW;

  if (t >= T) {                            // zero pad P row (content unused)
    uint2 z; z.x = 0u; z.y = 0u;
    *(uint2*)(prow + 4 * lane) = z;
    return;
  }

  const float* row = acts + ((size_t)t * B + b) * V;
  const float2 v2 = *(const float2*)(row + 2 * lane);
  const float e0 = exp2f(fmaf(v2.x, L2E, -32.0f));
  const float e1 = exp2f(fmaf(v2.y, L2E, -32.0f));
  const float sm = wave_sum_nn(e0 + e1);
  const float r  = __builtin_amdgcn_rcpf(sm);

  const auto pk = __builtin_amdgcn_cvt_pkrtz(e0 * r, e1 * r);
  uint hp;                                  // [p_{2l} | p_{2l+1} << 16]
  __builtin_memcpy(&hp, &pk, 4);

  // gather the 4 label probs this lane owns (labels 4l..4l+3)
  const int4 lv = *(const int4*)(labels + (size_t)b * L + 4 * lane);
  const uint g0 = (uint)__builtin_amdgcn_ds_bpermute((lv.x & ~1) * 2, (int)hp);
  const uint g1 = (uint)__builtin_amdgcn_ds_bpermute((lv.y & ~1) * 2, (int)hp);
  const uint g2 = (uint)__builtin_amdgcn_ds_bpermute((lv.z & ~1) * 2, (int)hp);
  const uint g3 = (uint)__builtin_amdgcn_ds_bpermute((lv.w & ~1) * 2, (int)hp);
  const uint h0 = (g0 >> ((lv.x & 1) << 4)) & 0xffffu;
  const uint h1 = (g1 >> ((lv.y & 1) << 4)) & 0xffffu;
  const uint h2 = (g2 >> ((lv.z & 1) << 4));
  const uint h3 = (g3 >> ((lv.w & 1) << 4));
  uint2 o;
  o.x = h0 | (h2 << 16);                    // pair (e0, e2)
  o.y = h1 | (h3 << 16);                    // pair (e1, e3)
  *(uint2*)(prow + 4 * lane) = o;
  if (lane == 0) {
    const float pb = e0 * r;                // vocab 0 = this lane's p0
    v2f bp; bp.x = pb; bp.y = pb;
    *(v2f*)(Pbk + ((size_t)b * TP + t + 1) * 2) = bp;
  }
}

// ---------------- DP kernel: one wave per batch ----------------
// Lane l owns cells 8l..8l+7 as pairs P0=(c0,c4) P1=(c1,c5) P2=(c2,c6)
// P3=(c3,c7); lane 63 additionally owns cell 512 in a8.
__global__ __launch_bounds__(64, 1) void ctc_dp_kernel(
    const ushort* __restrict__ P,
    const float* __restrict__ Pbk,
    const int* __restrict__ labels,
    const int* __restrict__ act_lens,
    const int* __restrict__ label_lens,
    float* __restrict__ out) {
  __shared__ uint lds[2 * LBUF];
  const int b    = blockIdx.x;
  const int lane = threadIdx.x;
  const ushort* __restrict__ Pb = P + (size_t)b * TP * RW;
  const float*  __restrict__ Bk = Pbk + (size_t)b * TP * 2;

  // skip-transition flags for the 4 odd cells (labels 4l..4l+3)
  const int4 lv   = *(const int4*)(labels + (size_t)b * L + 4 * lane);
  const int prevw = __builtin_amdgcn_update_dpp(0, lv.w, 0x138, 0xf, 0xf, true);
  const float f0 = (lane > 0 && lv.x != 0 && lv.x != prevw) ? 1.f : 0.f;
  const float f1 = (lv.y != 0 && lv.y != lv.x) ? 1.f : 0.f;
  const float f2 = (lv.z != 0 && lv.z != lv.y) ? 1.f : 0.f;
  const float f3 = (lv.w != 0 && lv.w != lv.z) ? 1.f : 0.f;
  v2f F02; F02.x = f0; F02.y = f2;          // skips into P1 = (c1, c5)
  v2f F13; F13.x = f1; F13.y = f3;          // skips into P3 = (c3, c7)

  const int AL = act_lens[b];

  // ---- t=0 init (linear domain; unreachable cells = 0) ----
  v2f P0, P1, P2, P3;
  P0.x=0.f; P0.y=0.f; P1.x=0.f; P1.y=0.f;
  P2.x=0.f; P2.y=0.f; P3.x=0.f; P3.y=0.f;
  float a8 = 0.f;
  {
    const uint2 u0 = *(const uint2*)(Pb + 4 * lane);
    const float eb0 = Bk[2];                // blank(t=0) at pair 1
    const float e00 = h2f(u0.x);            // label-0 prob at t=0 (pair lo)
    if (lane == 0) { P0.x = eb0; P1.x = e00; }
  }
  int iacc = 0;        // accumulated log2 of renorm scales (wave-uniform)
  float pend = 1.0f;   // wave-maxed state max, measured 4 steps before apply

  // Packed step: 1 DPP + 4 pk_add + 2 pk_fma + 4 pk_mul (+ a8 scalar pair).
  auto step = [&](v2u u, v2f eb) {
    const float pc = fdpp0<0x138>(P3.y);    // prev lane's c7 (lane0 -> 0)
    v2f Q; Q.x = pc; Q.y = P3.x;            // (c_{-1}, c3_old)
    v2f E02, E13;
    E02.x = h2f(u.x); E02.y = h2f(u.x >> 16);
    E13.x = h2f(u.y); E13.y = h2f(u.y >> 16);
    const v2f S0 = pk_add(P0, Q);           // (c0+pc,  c4+c3)
    const v2f S1 = pk_add(P1, P0);          // (c1+c0,  c5+c4)
    const v2f S2 = pk_add(P2, P1);          // (c2+c1,  c6+c5)
    const v2f S3 = pk_add(P3, P2);          // (c3+c2,  c7+c6)
    const v2f T1 = pk_fma(F02, Q,  S1);     // +f0*pc,  +f2*c3_old
    const v2f T3 = pk_fma(F13, P1, S3);     // +f1*c1_old, +f3*c5_old
    const float s8 = a8 + P3.y;             // cell 512 (valid on lane 63)
    P0 = pk_mul(S0, eb);
    P2 = pk_mul(S2, eb);
    P1 = pk_mul(T1, E02);
    P3 = pk_mul(T3, E13);
    a8 = s8 * eb.x;
  };

  auto measure = [&]() {                    // start wave-max; result used 4
    float m = fmaxf(fmaxf(fmaxf(P0.x, P0.y), fmaxf(P1.x, P1.y)),   // steps later
                    fmaxf(fmaxf(P2.x, P2.y), fmaxf(P3.x, P3.y)));
    m = fmaxf(m, a8);
    pend = wave_max(m);
  };
  auto apply = [&]() {                      // pow-2 scale, exact
    const uint mb = __float_as_uint(pend);
    int e = (int)((mb >> 23) & 0xffu); if (e < 1) e = 1;
    const float r = __uint_as_float((uint)(254 - e) << 23);
    iacc += (e - 127);
    v2f rr; rr.x = r; rr.y = r;
    P0 = pk_mul(P0, rr); P1 = pk_mul(P1, rr);
    P2 = pk_mul(P2, rr); P3 = pk_mul(P3, rr);
    a8 *= r;
  };

  // ---- staging: 9 DMA loads per 16-step block into LDS buffer bufi ----
  auto stage = [&](int bufi, int pblk) {
    uint* lb = &lds[bufi * LBUF];
    const uint* gp = (const uint*)(Pb + (size_t)(1 + 16 * pblk) * RW) + lane * 4;
    #pragma unroll
    for (int r2 = 0; r2 < 8; ++r2)
      gl_lds16(gp + r2 * 256, lb + r2 * 256);
    const uint* gb = (const uint*)(Bk + (size_t)(2 + 16 * pblk) * 2) + lane;
    gl_lds4(gb, lb + 2048);
  };

  const uint lbase = (uint)(size_t)((as3_uint*)lds);   // raw LDS byte offset

// One pipelined step: copy pair K, issue pair K+4 (if K<12), dataflow wait,
// then the DP step (GUARD = conditional execution for tail blocks).
#define PSTEP(K, NW, GUARD)                                                  \
  {                                                                          \
    v2u u = U[(K) & 3]; v2f eb = E[(K) & 3];                                 \
    if ((K) < 12) {                                                          \
      dsr64<(((K) + 4) * 512)>(U[(K) & 3], ua);                              \
      dsr64f<(((K) + 4) * 8)>(E[(K) & 3], eadr);                             \
    }                                                                        \
    waitpair<NW>(u, eb);                                                     \
    GUARD step(u, eb);                                                       \
    if ((K) == 3 || (K) == 11) measure();                                    \
    if ((K) == 7 || (K) == 15) apply();                                      \
  }

  auto compute_blk = [&](int bufi, int tb, bool fast) {
    const uint lb   = lbase + (uint)bufi * (uint)(LBUF * 4);
    const uint ua   = lb + (uint)lane * 8u;
    const uint eadr = lb + 8192u;
    v2u U[4]; v2f E[4];
    dsr64<0>(U[0], ua);    dsr64f<0>(E[0], eadr);
    dsr64<512>(U[1], ua);  dsr64f<8>(E[1], eadr);
    dsr64<1024>(U[2], ua); dsr64f<16>(E[2], eadr);
    dsr64<1536>(U[3], ua); dsr64f<24>(E[3], eadr);
    if (fast) {
      PSTEP(0, 8, )  PSTEP(1, 8, )  PSTEP(2, 8, )  PSTEP(3, 8, )
      PSTEP(4, 8, )  PSTEP(5, 8, )  PSTEP(6, 8, )  PSTEP(7, 8, )
      PSTEP(8, 8, )  PSTEP(9, 8, )  PSTEP(10, 8, ) PSTEP(11, 8, )
      PSTEP(12, 6, ) PSTEP(13, 4, ) PSTEP(14, 2, ) PSTEP(15, 0, )
    } else {
      PSTEP(0, 8, if ((tb + 0) < AL))   PSTEP(1, 8, if ((tb + 1) < AL))
      PSTEP(2, 8, if ((tb + 2) < AL))   PSTEP(3, 8, if ((tb + 3) < AL))
      PSTEP(4, 8, if ((tb + 4) < AL))   PSTEP(5, 8, if ((tb + 5) < AL))
      PSTEP(6, 8, if ((tb + 6) < AL))   PSTEP(7, 8, if ((tb + 7) < AL))
      PSTEP(8, 8, if ((tb + 8) < AL))   PSTEP(9, 8, if ((tb + 9) < AL))
      PSTEP(10, 8, if ((tb + 10) < AL)) PSTEP(11, 8, if ((tb + 11) < AL))
      PSTEP(12, 6, if ((tb + 12) < AL)) PSTEP(13, 4, if ((tb + 13) < AL))
      PSTEP(14, 2, if ((tb + 14) < AL)) PSTEP(15, 0, if ((tb + 15) < AL))
    }
  };

  stage(0, 0);
  stage(1, 1);

  int t0 = 1;
  #pragma unroll 1
  for (int it = 0; it < 64; ++it) {
    const int cur = it & 1;
    asm volatile("s_waitcnt vmcnt(9)" ::: "memory");    // block `it` landed
    compute_blk(cur, t0, (t0 + 16) <= AL);
    asm volatile("s_waitcnt lgkmcnt(0)" ::: "memory");  // buf reads done
    int nb = it + 2; if (nb > 63) nb = 63;              // clamped: vmcnt const
    stage(cur, nb);
    t0 += 16;
  }

  // ---- epilogue: -ln( (a[end] + a[end-1]) * 2^iacc ) ----
  // cell map: base+0=P0.x +1=P1.x +2=P2.x +3=P3.x +4=P0.y +5=P1.y +6=P2.y +7=P3.y
  const int end  = 2 * label_lens[b];
  const int base = 8 * lane;
  float sel = 0.f;
  if (base     == end || base     == end - 1) sel += P0.x;
  if (base + 1 == end || base + 1 == end - 1) sel += P1.x;
  if (base + 2 == end || base + 2 == end - 1) sel += P2.x;
  if (base + 3 == end || base + 3 == end - 1) sel += P3.x;
  if (base + 4 == end || base + 4 == end - 1) sel += P0.y;
  if (base + 5 == end || base + 5 == end - 1) sel += P1.y;
  if (base + 6 == end || base + 6 == end - 1) sel += P2.y;
  if (base + 7 == end || base + 7 == end - 1) sel += P3.y;
  if (lane == 63 && (end == 512 || end - 1 == 512)) sel += a8;
  sel = wave_sum_nn(sel);
  if (lane == 0) {
    const float cost = -((log2f(sel) + (float)iacc) * LN2);
    atomicAdd(out, cost);
  }
}

extern "C" void kernel_launch(void* const* d_in, const int* in_sizes, int n_in,
                              void* d_out, int out_size, void* d_ws, size_t ws_size,
                              hipStream_t stream) {
  const float* acts       = (const float*)d_in[0];
  const int*   labels     = (const int*)d_in[1];
  const int*   act_lens   = (const int*)d_in[2];
  const int*   label_lens = (const int*)d_in[3];
  float* out = (float*)d_out;
  ushort* P   = (ushort*)d_ws;                       // B*TP*512B = 34.6 MB
  float*  Pbk = (float*)(P + (size_t)B * TP * RW);   // B*TP*8B   = 0.54 MB

  (void)hipMemsetAsync(out, 0, sizeof(float) * out_size, stream);
  ctc_probs_kernel<<<dim3(TP / 8, B), 512, 0, stream>>>(acts, labels, P, Pbk);
  ctc_dp_kernel<<<B, 64, 0, stream>>>(P, Pbk, labels, act_lens, label_lens, out);
}

// Round 10
// 146.619 us; speedup vs baseline: 1.0352x; 1.0264x over previous
//
#include <hip/hip_runtime.h>
#include <hip/hip_fp16.h>
#include <math.h>

// CTC forward loss (warp-ctc semantics). T=1024, B=64, V=128, L=256, S=513.
//
// Round 11: instruction-count attack. Evidence R4/R7/R8/R9: per-step cost
// ~146-166 cyc across four memory schemes -> memory is NOT the stall;
// VALUBusy says ~42 VALU instrs/step. This round: R4's structure (plain
// compiler-scheduled global loads -- the best-measured variant) minus
// freight: renorm every 16 steps (was 8) with +48 exponent headroom on the
// pow-2 scale (measure@13, apply@15; tolerates per-step max-decay down to
// ~2^-9.7, typical is ~2^-4), single Q-mov, dual load bases so all global
// offsets fit the 13-bit immediate (no per-step 64-bit address adds).

#define L2E 1.4426950408889634f
#define LN2 0.6931471805599453f

constexpr int T   = 1024;
constexpr int B   = 64;
constexpr int V   = 128;
constexpr int L   = 256;
constexpr int RW  = 256;        // ushorts per P row: 256 label probs = 512 B
constexpr int TP  = T + 32;     // padded time rows per batch

typedef float v2f __attribute__((ext_vector_type(2)));
typedef unsigned int v2u __attribute__((ext_vector_type(2)));

// ---- VOP3P packed-fp32 helpers (gfx90a+; full-rate dual fp32) ----
__device__ __forceinline__ v2f pk_add(v2f a, v2f b) {
  v2f d; asm("v_pk_add_f32 %0, %1, %2" : "=v"(d) : "v"(a), "v"(b)); return d;
}
__device__ __forceinline__ v2f pk_mul(v2f a, v2f b) {
  v2f d; asm("v_pk_mul_f32 %0, %1, %2" : "=v"(d) : "v"(a), "v"(b)); return d;
}
__device__ __forceinline__ v2f pk_fma(v2f a, v2f b, v2f c) {
  v2f d; asm("v_pk_fma_f32 %0, %1, %2, %3" : "=v"(d) : "v"(a), "v"(b), "v"(c));
  return d;
}

// ---- DPP helpers (gfx9 ctrl codes: 0x111+ row_shr, 0x138 wave_shr:1,
//      0x142 row_bcast15, 0x143 row_bcast31) ----
template <int CTRL>
__device__ __forceinline__ float fdpp0(float x) {        // invalid lanes -> 0
  return __int_as_float(__builtin_amdgcn_update_dpp(
      0, __float_as_int(x), CTRL, 0xf, 0xf, true));
}
template <int CTRL>
__device__ __forceinline__ float fdppk(float x) {        // invalid lanes -> keep
  return __int_as_float(__builtin_amdgcn_update_dpp(
      __float_as_int(x), __float_as_int(x), CTRL, 0xf, 0xf, false));
}

__device__ __forceinline__ float wave_bcast63(float x) {
  return __int_as_float(__builtin_amdgcn_readlane(__float_as_int(x), 63));
}

__device__ __forceinline__ float wave_max(float x) {     // any sign
  x = fmaxf(x, fdppk<0x111>(x));
  x = fmaxf(x, fdppk<0x112>(x));
  x = fmaxf(x, fdppk<0x114>(x));
  x = fmaxf(x, fdppk<0x118>(x));
  x = fmaxf(x, fdppk<0x142>(x));
  x = fmaxf(x, fdppk<0x143>(x));
  return wave_bcast63(x);
}
__device__ __forceinline__ float wave_sum_nn(float x) {  // x >= 0
  x += fdpp0<0x111>(x);
  x += fdpp0<0x112>(x);
  x += fdpp0<0x114>(x);
  x += fdpp0<0x118>(x);
  x += fdpp0<0x142>(x);
  x += fdpp0<0x143>(x);
  return wave_bcast63(x);
}

__device__ __forceinline__ float h2f(uint bits) {
  return __half2float(__ushort_as_half((ushort)bits));
}

// ---------------- prologue: emission probabilities ----------------
// One wave per (t, b) row. Softmax entirely in registers; ds_bpermute label
// gathers. Output PAIRED for the DP: u.x=(e0|e2<<16), u.y=(e1|e3<<16).
// Blank(t) stored as a duplicated fp32 pair at pair index t.
__global__ __launch_bounds__(512) void ctc_probs_kernel(
    const float* __restrict__ acts,        // (T, B, V)
    const int* __restrict__ labels,        // (B, L)
    ushort* __restrict__ P,                // (B, TP, RW) fp16 bits, 512B rows
    float* __restrict__ Pbk) {             // (B, TP) duplicated fp32 pairs
  const int w    = threadIdx.x >> 6;
  const int lane = threadIdx.x & 63;
  const int t    = blockIdx.x * 8 + w;     // t in [0, TP)
  const int b    = blockIdx.y;
  ushort* prow = P + ((size_t)b * TP + t) * RW;

  if (t >= T) {                            // zero pad row (content unused)
    uint2 z; z.x = 0u; z.y = 0u;
    *(uint2*)(prow + 4 * lane) = z;
    if (lane == 0) {
      v2f zp; zp.x = 0.f; zp.y = 0.f;
      *(v2f*)(Pbk + ((size_t)b * TP + t) * 2) = zp;
    }
    return;
  }

  const float* row = acts + ((size_t)t * B + b) * V;
  const float2 v2 = *(const float2*)(row + 2 * lane);
  const float e0 = exp2f(fmaf(v2.x, L2E, -32.0f));
  const float e1 = exp2f(fmaf(v2.y, L2E, -32.0f));
  const float sm = wave_sum_nn(e0 + e1);
  const float r  = __builtin_amdgcn_rcpf(sm);

  const auto pk = __builtin_amdgcn_cvt_pkrtz(e0 * r, e1 * r);
  uint hp;                                  // [p_{2l} | p_{2l+1} << 16]
  __builtin_memcpy(&hp, &pk, 4);

  // gather the 4 label probs this lane owns (labels 4l..4l+3)
  const int4 lv = *(const int4*)(labels + (size_t)b * L + 4 * lane);
  const uint g0 = (uint)__builtin_amdgcn_ds_bpermute((lv.x & ~1) * 2, (int)hp);
  const uint g1 = (uint)__builtin_amdgcn_ds_bpermute((lv.y & ~1) * 2, (int)hp);
  const uint g2 = (uint)__builtin_amdgcn_ds_bpermute((lv.z & ~1) * 2, (int)hp);
  const uint g3 = (uint)__builtin_amdgcn_ds_bpermute((lv.w & ~1) * 2, (int)hp);
  const uint h0 = (g0 >> ((lv.x & 1) << 4)) & 0xffffu;
  const uint h1 = (g1 >> ((lv.y & 1) << 4)) & 0xffffu;
  const uint h2 = (g2 >> ((lv.z & 1) << 4));
  const uint h3 = (g3 >> ((lv.w & 1) << 4));
  uint2 o;
  o.x = h0 | (h2 << 16);                    // pair (e0, e2)
  o.y = h1 | (h3 << 16);                    // pair (e1, e3)
  *(uint2*)(prow + 4 * lane) = o;
  if (lane == 0) {
    const float pb = e0 * r;                // vocab 0 = this lane's p0
    v2f bp; bp.x = pb; bp.y = pb;
    *(v2f*)(Pbk + ((size_t)b * TP + t) * 2) = bp;
  }
}

// ---------------- DP kernel: one wave per batch ----------------
// Lane l owns cells 8l..8l+7 as pairs P0=(c0,c4) P1=(c1,c5) P2=(c2,c6)
// P3=(c3,c7); lane 63 additionally owns cell 512 in a8.
__global__ __launch_bounds__(64) void ctc_dp_kernel(
    const ushort* __restrict__ P,
    const float* __restrict__ Pbk,
    const int* __restrict__ labels,
    const int* __restrict__ act_lens,
    const int* __restrict__ label_lens,
    float* __restrict__ out) {
  const int b    = blockIdx.x;
  const int lane = threadIdx.x;
  const ushort* __restrict__ Pb = P + (size_t)b * TP * RW;
  const float*  __restrict__ Bk = Pbk + (size_t)b * TP * 2;

  // skip-transition flags for the 4 odd cells (labels 4l..4l+3)
  const int4 lv   = *(const int4*)(labels + (size_t)b * L + 4 * lane);
  const int prevw = __builtin_amdgcn_update_dpp(0, lv.w, 0x138, 0xf, 0xf, true);
  const float f0 = (lane > 0 && lv.x != 0 && lv.x != prevw) ? 1.f : 0.f;
  const float f1 = (lv.y != 0 && lv.y != lv.x) ? 1.f : 0.f;
  const float f2 = (lv.z != 0 && lv.z != lv.y) ? 1.f : 0.f;
  const float f3 = (lv.w != 0 && lv.w != lv.z) ? 1.f : 0.f;
  v2f F02; F02.x = f0; F02.y = f2;          // skips into P1 = (c1, c5)
  v2f F13; F13.x = f1; F13.y = f3;          // skips into P3 = (c3, c7)

  const int AL = act_lens[b];

  // ---- t=0 init (linear domain; unreachable cells = 0) ----
  v2f P0, P1, P2, P3;
  P0.x=0.f; P0.y=0.f; P1.x=0.f; P1.y=0.f;
  P2.x=0.f; P2.y=0.f; P3.x=0.f; P3.y=0.f;
  float a8 = 0.f;
  {
    const uint2 u0 = *(const uint2*)(Pb + 4 * lane);
    const v2f bk0  = *(const v2f*)(Bk);
    const float eb0 = bk0.x;                // blank prob at t=0
    const float e00 = h2f(u0.x);            // label-0 prob at t=0 (pair lo)
    if (lane == 0) { P0.x = eb0; P1.x = e00; }
  }
  int iacc = 0;        // accumulated log2 of renorm scales (wave-uniform)
  float pend = 1.0f;   // wave-maxed state max, measured 2 steps before apply

  // Packed step: 1 DPP + 1 mov + 4 cvt + 4 pk_add + 2 pk_fma + 4 pk_mul
  // (+ 2 scalar for a8).
  auto step = [&](v2u u, v2f eb) {
    const float pc = fdpp0<0x138>(P3.y);    // prev lane's c7 (lane0 -> 0)
    v2f Q; Q.x = pc; Q.y = P3.x;            // (c_{-1}, c3_old)
    v2f E02, E13;
    E02.x = h2f(u.x); E02.y = h2f(u.x >> 16);
    E13.x = h2f(u.y); E13.y = h2f(u.y >> 16);
    const float s8 = a8 + P3.y;             // cell 512 (valid on lane 63)
    const v2f S3 = pk_add(P3, P2);          // (c3+c2,  c7+c6)
    const v2f T3 = pk_fma(F13, P1, S3);     // +f1*c1_old, +f3*c5_old
    const v2f S2 = pk_add(P2, P1);          // (c2+c1,  c6+c5)
    const v2f S1 = pk_add(P1, P0);          // (c1+c0,  c5+c4)
    const v2f S0 = pk_add(P0, Q);           // (c0+pc,  c4+c3)
    const v2f T1 = pk_fma(F02, Q,  S1);     // +f0*pc,  +f2*c3_old
    P3 = pk_mul(T3, E13);                   // early: distance to next DPP
    P2 = pk_mul(S2, eb);
    P1 = pk_mul(T1, E02);
    P0 = pk_mul(S0, eb);
    a8 = s8 * eb.x;
  };

  auto measure = [&]() {                    // start wave-max; used 2 steps on
    float m = fmaxf(fmaxf(fmaxf(P0.x, P0.y), fmaxf(P1.x, P1.y)),
                    fmaxf(fmaxf(P2.x, P2.y), fmaxf(P3.x, P3.y)));
    m = fmaxf(m, a8);
    pend = wave_max(m);
  };
  auto apply = [&]() {                      // pow-2 scale 2^(175-e), exact.
    // +48 headroom: post-apply max ~2^48*d^2; 16-step dip stays normal for
    // per-step max-decay d >= 2^-9.7 (typical d ~ 2^-4). e clamped so the
    // exponent field (302-e) stays valid; tiny/flushed max recovers.
    const uint mb = __float_as_uint(pend);
    int e = (int)((mb >> 23) & 0xffu); if (e < 48) e = 48;
    const float r = __uint_as_float((uint)(302 - e) << 23);
    iacc += (e - 175);
    v2f rr; rr.x = r; rr.y = r;
    P0 = pk_mul(P0, rr); P1 = pk_mul(P1, rr);
    P2 = pk_mul(P2, rr); P3 = pk_mul(P3, rr);
    a8 *= r;
  };

  // ---- prefetch pipeline: depth 16 (rows t .. t+15) ----
  uint2 evi[16];
  v2f   ebk[16];
  #pragma unroll
  for (int k = 0; k < 16; ++k) {
    evi[k] = *(const uint2*)(Pb + (size_t)(1 + k) * RW + 4 * lane);
    ebk[k] = *(const v2f*)(Bk + (size_t)(1 + k) * 2);
  }

  const ushort* pf = Pb + (size_t)17 * RW;  // row t+16 for t=1
  const float*  bf = Bk + (size_t)17 * 2;
  int t0 = 1;
  #pragma unroll 1
  for (int blk = 0; blk < 64; ++blk) {      // 64 x 16 = steps t=1..1024
    const ushort* pfA = pf;                 // dual bases: offsets <= 3584+8*63
    const ushort* pfB = pf + (size_t)8 * RW;
    const bool fast = (t0 + 16 <= AL);
    if (fast) {
      #pragma unroll
      for (int k = 0; k < 16; ++k) {
        const uint2 uu = evi[k];
        v2u u; u.x = uu.x; u.y = uu.y;
        const v2f  eb = ebk[k];
        evi[k] = *(const uint2*)(((k < 8) ? pfA : pfB)
                                 + (size_t)(k & 7) * RW + 4 * lane);
        ebk[k] = *(const v2f*)(bf + (size_t)k * 2);
        step(u, eb);
        if (k == 13) measure();
        if (k == 15) apply();
      }
    } else {
      #pragma unroll
      for (int k = 0; k < 16; ++k) {
        const uint2 uu = evi[k];
        v2u u; u.x = uu.x; u.y = uu.y;
        const v2f  eb = ebk[k];
        evi[k] = *(const uint2*)(((k < 8) ? pfA : pfB)
                                 + (size_t)(k & 7) * RW + 4 * lane);
        ebk[k] = *(const v2f*)(bf + (size_t)k * 2);
        if ((t0 + k) < AL) step(u, eb);     // AL wave-uniform: scalar branch
        if (k == 13) measure();
        if (k == 15) apply();
      }
    }
    t0 += 16;
    pf += (size_t)16 * RW;
    bf += (size_t)16 * 2;
  }

  // ---- epilogue: -ln( (a[end] + a[end-1]) * 2^iacc ) ----
  // cell map: base+0=P0.x +1=P1.x +2=P2.x +3=P3.x +4=P0.y +5=P1.y +6=P2.y +7=P3.y
  const int end  = 2 * label_lens[b];
  const int base = 8 * lane;
  float sel = 0.f;
  if (base     == end || base     == end - 1) sel += P0.x;
  if (base + 1 == end || base + 1 == end - 1) sel += P1.x;
  if (base + 2 == end || base + 2 == end - 1) sel += P2.x;
  if (base + 3 == end || base + 3 == end - 1) sel += P3.x;
  if (base + 4 == end || base + 4 == end - 1) sel += P0.y;
  if (base + 5 == end || base + 5 == end - 1) sel += P1.y;
  if (base + 6 == end || base + 6 == end - 1) sel += P2.y;
  if (base + 7 == end || base + 7 == end - 1) sel += P3.y;
  if (lane == 63 && (end == 512 || end - 1 == 512)) sel += a8;
  sel = wave_sum_nn(sel);
  if (lane == 0) {
    const float cost = -((log2f(sel) + (float)iacc) * LN2);
    atomicAdd(out, cost);
  }
}

extern "C" void kernel_launch(void* const* d_in, const int* in_sizes, int n_in,
                              void* d_out, int out_size, void* d_ws, size_t ws_size,
                              hipStream_t stream) {
  const float* acts       = (const float*)d_in[0];
  const int*   labels     = (const int*)d_in[1];
  const int*   act_lens   = (const int*)d_in[2];
  const int*   label_lens = (const int*)d_in[3];
  float* out = (float*)d_out;
  ushort* P   = (ushort*)d_ws;                       // B*TP*512B = 34.6 MB
  float*  Pbk = (float*)(P + (size_t)B * TP * RW);   // B*TP*8B   = 0.54 MB

  (void)hipMemsetAsync(out, 0, sizeof(float) * out_size, stream);
  ctc_probs_kernel<<<dim3(TP / 8, B), 512, 0, stream>>>(acts, labels, P, Pbk);
  ctc_dp_kernel<<<B, 64, 0, stream>>>(P, Pbk, labels, act_lens, label_lens, out);
}